// Round 2
// baseline (1436.710 us; speedup 1.0000x reference)
//
#include <hip/hip_runtime.h>

#define N_NODES 100000
#define N_EDGES 3200000
#define F_IN 1433
#define F_HID 16
#define F_OUT 7

// ---------------- CSR build ----------------

__global__ __launch_bounds__(256) void k_deg(const int* __restrict__ src, const int* __restrict__ dst,
                                             int* __restrict__ deg_out, int* __restrict__ deg_in) {
    int e = blockIdx.x * 256 + threadIdx.x;
    if (e < N_EDGES) {
        atomicAdd(&deg_out[src[e]], 1);
        atomicAdd(&deg_in[dst[e]], 1);
    }
}

// block sums of deg_in, 1024 elems/block
__global__ __launch_bounds__(256) void k_scan1(const int* __restrict__ deg, int* __restrict__ blockSums) {
    int base = blockIdx.x * 1024 + threadIdx.x * 4;
    int s = 0;
#pragma unroll
    for (int i = 0; i < 4; i++) { int idx = base + i; if (idx < N_NODES) s += deg[idx]; }
#pragma unroll
    for (int d = 1; d < 64; d <<= 1) s += __shfl_xor(s, d);
    __shared__ int lds[4];
    int wid = threadIdx.x >> 6;
    if ((threadIdx.x & 63) == 0) lds[wid] = s;
    __syncthreads();
    if (threadIdx.x == 0) blockSums[blockIdx.x] = lds[0] + lds[1] + lds[2] + lds[3];
}

// exclusive scan of 98 block sums, single wave
__global__ void k_scan2(const int* __restrict__ blockSums, int* __restrict__ blockOffs) {
    const int nb = 98;
    int l = threadIdx.x;
    int a = (l < nb) ? blockSums[l] : 0;
    int b = (64 + l < nb) ? blockSums[64 + l] : 0;
    int ia = a, ib = b;
#pragma unroll
    for (int d = 1; d < 64; d <<= 1) { int t = __shfl_up(ia, d); if (l >= d) ia += t; }
    int totA = __shfl(ia, 63);
#pragma unroll
    for (int d = 1; d < 64; d <<= 1) { int t = __shfl_up(ib, d); if (l >= d) ib += t; }
    if (l < nb) blockOffs[l] = ia - a;
    if (64 + l < nb) blockOffs[64 + l] = totA + ib - b;
}

// full exclusive scan -> offsets
__global__ __launch_bounds__(256) void k_scan3(const int* __restrict__ deg, const int* __restrict__ blockOffs,
                                               int* __restrict__ offsets) {
    int t = threadIdx.x, b = blockIdx.x;
    int base = b * 1024 + t * 4;
    int v[4]; int s = 0;
#pragma unroll
    for (int i = 0; i < 4; i++) { int idx = base + i; v[i] = (idx < N_NODES) ? deg[idx] : 0; s += v[i]; }
    int incl = s;
    int lane = t & 63, wid = t >> 6;
#pragma unroll
    for (int d = 1; d < 64; d <<= 1) { int x = __shfl_up(incl, d); if (lane >= d) incl += x; }
    __shared__ int wsum[4];
    if (lane == 63) wsum[wid] = incl;
    __syncthreads();
    int wbase = 0;
    for (int w = 0; w < wid; w++) wbase += wsum[w];
    int ex = blockOffs[b] + wbase + incl - s;
#pragma unroll
    for (int i = 0; i < 4; i++) { int idx = base + i; if (idx < N_NODES) offsets[idx] = ex; ex += v[i]; }
}

__global__ __launch_bounds__(256) void k_fill(const int* __restrict__ src, const int* __restrict__ dst,
                                              const int* __restrict__ offsets, int* __restrict__ cursor,
                                              int* __restrict__ csr_src) {
    int e = blockIdx.x * 256 + threadIdx.x;
    if (e < N_EDGES) {
        int d = dst[e];
        int pos = offsets[d] + atomicAdd(&cursor[d], 1);
        csr_src[pos] = src[e];
    }
}

__global__ __launch_bounds__(256) void k_norm(const int* __restrict__ deg_out, const int* __restrict__ deg_in,
                                              float* __restrict__ ns, float* __restrict__ nd_) {
    int i = blockIdx.x * 256 + threadIdx.x;
    if (i < N_NODES) {
        ns[i] = rsqrtf((float)max(deg_out[i], 1));
        nd_[i] = rsqrtf((float)max(deg_in[i], 1));
    }
}

// ---------------- layer 1 matmul: h1 = (feat .* ns) @ W1 ----------------
// wave = 8 rows; lane = (kq = lane&15, j4 = lane>>4); lane owns k = 4kq+i (mod 64-chunk), j-quad j4.
__global__ __launch_bounds__(256) void k_mm1(const float* __restrict__ feat, const float* __restrict__ W1,
                                             const float* __restrict__ ns, float* __restrict__ h1) {
    const int lane = threadIdx.x & 63;
    const int wid = threadIdx.x >> 6;
    const int kq = lane & 15, j4 = lane >> 4;
    const int r0 = (blockIdx.x * 4 + wid) * 8;   // 3125*4*8 = 100000 exactly
    const float4* __restrict__ W4 = (const float4*)W1;
    float4 acc[8];
#pragma unroll
    for (int rr = 0; rr < 8; rr++) acc[rr] = make_float4(0.f, 0.f, 0.f, 0.f);
    const float* __restrict__ fbase = feat + (size_t)r0 * F_IN;

    for (int kk = 0; kk < 22; kk++) {          // k in [0, 1408)
        int kb = kk * 64 + kq * 4;
        float4 w[4];
#pragma unroll
        for (int i = 0; i < 4; i++) w[i] = W4[(kb + i) * 4 + j4];
#pragma unroll
        for (int rr = 0; rr < 8; rr++) {
            const float* fr = fbase + rr * F_IN + kb;
            float f0 = fr[0], f1 = fr[1], f2 = fr[2], f3 = fr[3];
            acc[rr].x += f0 * w[0].x; acc[rr].y += f0 * w[0].y; acc[rr].z += f0 * w[0].z; acc[rr].w += f0 * w[0].w;
            acc[rr].x += f1 * w[1].x; acc[rr].y += f1 * w[1].y; acc[rr].z += f1 * w[1].z; acc[rr].w += f1 * w[1].w;
            acc[rr].x += f2 * w[2].x; acc[rr].y += f2 * w[2].y; acc[rr].z += f2 * w[2].z; acc[rr].w += f2 * w[2].w;
            acc[rr].x += f3 * w[3].x; acc[rr].y += f3 * w[3].y; acc[rr].z += f3 * w[3].z; acc[rr].w += f3 * w[3].w;
        }
    }
    // tail: k in [1408, 1433)
#pragma unroll
    for (int s = 0; s < 2; s++) {
        int k = 1408 + s * 16 + kq;
        bool valid = (k < F_IN);
        float4 w = valid ? W4[k * 4 + j4] : make_float4(0.f, 0.f, 0.f, 0.f);
#pragma unroll
        for (int rr = 0; rr < 8; rr++) {
            float f = valid ? fbase[rr * F_IN + k] : 0.f;
            acc[rr].x += f * w.x; acc[rr].y += f * w.y; acc[rr].z += f * w.z; acc[rr].w += f * w.w;
        }
    }
    // reduce across the 16 kq lanes (same j4 within each 16-lane group)
#pragma unroll
    for (int d = 1; d <= 8; d <<= 1) {
#pragma unroll
        for (int rr = 0; rr < 8; rr++) {
            acc[rr].x += __shfl_xor(acc[rr].x, d);
            acc[rr].y += __shfl_xor(acc[rr].y, d);
            acc[rr].z += __shfl_xor(acc[rr].z, d);
            acc[rr].w += __shfl_xor(acc[rr].w, d);
        }
    }
    // lane kq==rr writes row rr's j-quad (4 lanes x 16B = 64B per row)
#pragma unroll
    for (int rr = 0; rr < 8; rr++) {
        if (kq == rr) {
            float s = ns[r0 + rr];
            float4 o = make_float4(acc[rr].x * s, acc[rr].y * s, acc[rr].z * s, acc[rr].w * s);
            *(float4*)(h1 + (size_t)(r0 + rr) * F_HID + j4 * 4) = o;
        }
    }
}

// ---------------- gather 1: x = relu(segsum(h1[src]) * nd + b1) ----------------
__global__ __launch_bounds__(256) void k_gather1(const float* __restrict__ h1, const int* __restrict__ csr_src,
                                                 const int* __restrict__ offsets, const int* __restrict__ deg_in,
                                                 const float* __restrict__ nd_, const float* __restrict__ b1,
                                                 float* __restrict__ x) {
    int node = (blockIdx.x * 256 + threadIdx.x) >> 6;
    if (node >= N_NODES) return;
    int lane = threadIdx.x & 63;
    int j = lane & 15, e4 = lane >> 4;
    int off = offsets[node], deg = deg_in[node];
    float acc = 0.f;
    for (int it = e4; it < deg; it += 4) {
        int s = csr_src[off + it];
        acc += h1[(size_t)s * F_HID + j];
    }
    acc += __shfl_xor(acc, 16);
    acc += __shfl_xor(acc, 32);
    if (lane < 16) {
        float v = acc * nd_[node] + b1[j];
        x[(size_t)node * F_HID + j] = fmaxf(v, 0.f);
    }
}

// ---------------- layer 2 matmul: h2 = (x .* ns) @ W2 (row stride 8) ----------------
__global__ __launch_bounds__(256) void k_mm2(const float* __restrict__ x, const float* __restrict__ W2,
                                             const float* __restrict__ ns, float* __restrict__ h2) {
    int r = blockIdx.x * 256 + threadIdx.x;
    if (r >= N_NODES) return;
    const float4* __restrict__ xr = (const float4*)(x + (size_t)r * F_HID);
    float xv[16];
#pragma unroll
    for (int q = 0; q < 4; q++) {
        float4 v = xr[q];
        xv[q * 4 + 0] = v.x; xv[q * 4 + 1] = v.y; xv[q * 4 + 2] = v.z; xv[q * 4 + 3] = v.w;
    }
    float o[7];
#pragma unroll
    for (int c = 0; c < 7; c++) o[c] = 0.f;
#pragma unroll
    for (int j = 0; j < 16; j++) {
        float xj = xv[j];
#pragma unroll
        for (int c = 0; c < 7; c++) o[c] += xj * W2[j * 7 + c];
    }
    float s = ns[r];
    float4 lo = make_float4(o[0] * s, o[1] * s, o[2] * s, o[3] * s);
    float4 hi = make_float4(o[4] * s, o[5] * s, o[6] * s, 0.f);
    float4* hr = (float4*)(h2 + (size_t)r * 8);
    hr[0] = lo; hr[1] = hi;
}

// ---------------- gather 2: out = segsum(h2[src]) * nd + b2 ----------------
__global__ __launch_bounds__(256) void k_gather2(const float* __restrict__ h2, const int* __restrict__ csr_src,
                                                 const int* __restrict__ offsets, const int* __restrict__ deg_in,
                                                 const float* __restrict__ nd_, const float* __restrict__ b2,
                                                 float* __restrict__ out) {
    int node = (blockIdx.x * 256 + threadIdx.x) >> 6;
    if (node >= N_NODES) return;
    int lane = threadIdx.x & 63;
    int c = lane & 7, e8 = lane >> 3;
    int off = offsets[node], deg = deg_in[node];
    float acc = 0.f;
    for (int it = e8; it < deg; it += 8) {
        int s = csr_src[off + it];
        acc += h2[(size_t)s * 8 + c];
    }
    acc += __shfl_xor(acc, 8);
    acc += __shfl_xor(acc, 16);
    acc += __shfl_xor(acc, 32);
    if (lane < 7) {
        out[(size_t)node * F_OUT + lane] = acc * nd_[node] + b2[lane];
    }
}

extern "C" void kernel_launch(void* const* d_in, const int* in_sizes, int n_in,
                              void* d_out, int out_size, void* d_ws, size_t ws_size,
                              hipStream_t stream) {
    const float* feat = (const float*)d_in[0];
    const int* src = (const int*)d_in[1];
    const int* dst = (const int*)d_in[2];
    const float* W1 = (const float*)d_in[3];
    const float* b1 = (const float*)d_in[4];
    const float* W2 = (const float*)d_in[5];
    const float* b2 = (const float*)d_in[6];
    float* out = (float*)d_out;

    char* ws = (char*)d_ws;
    int* deg_out_i = (int*)(ws + 0);          // 400000 B
    int* deg_in_i  = (int*)(ws + 400000);     // 400000 B
    int* cursor    = (int*)(ws + 800000);     // 400000 B   (first 1.2MB zeroed)
    float* ns      = (float*)(ws + 1200000);
    float* nd_     = (float*)(ws + 1600000);
    int* offsets   = (int*)(ws + 2000000);
    int* blockSums = (int*)(ws + 2400000);
    int* blockOffs = (int*)(ws + 2400512);
    int* csr_src   = (int*)(ws + 2401024);    // 12.8 MB
    float* h1      = (float*)(ws + 15201024); // 6.4 MB
    float* x       = (float*)(ws + 21601024); // 6.4 MB
    float* h2      = (float*)(ws + 28001024); // 3.2 MB  (total ~31.2 MB)

    hipMemsetAsync(ws, 0, 1200000, stream);
    k_deg<<<12500, 256, 0, stream>>>(src, dst, deg_out_i, deg_in_i);
    k_scan1<<<98, 256, 0, stream>>>(deg_in_i, blockSums);
    k_scan2<<<1, 64, 0, stream>>>(blockSums, blockOffs);
    k_scan3<<<98, 256, 0, stream>>>(deg_in_i, blockOffs, offsets);
    k_fill<<<12500, 256, 0, stream>>>(src, dst, offsets, cursor, csr_src);
    k_norm<<<391, 256, 0, stream>>>(deg_out_i, deg_in_i, ns, nd_);
    k_mm1<<<3125, 256, 0, stream>>>(feat, W1, ns, h1);
    k_gather1<<<25000, 256, 0, stream>>>(h1, csr_src, offsets, deg_in_i, nd_, b1, x);
    k_mm2<<<391, 256, 0, stream>>>(x, W2, ns, h2);
    k_gather2<<<25000, 256, 0, stream>>>(h2, csr_src, offsets, deg_in_i, nd_, b2, out);
}